// Round 11
// baseline (173.044 us; speedup 1.0000x reference)
//
#include <hip/hip_runtime.h>
#include <hip/hip_bf16.h>

constexpr int B_ = 4;
constexpr int L_ = 2048;
constexpr int D_ = 256;
constexpr int P_ = 32;
constexpr int CL = 32;   // chunk length for KV scan
constexpr int NC = L_ / CL;  // 64 chunks

#define PI_F 3.14159265358979323846f
#define INV_SQRT_P 0.17677669529663687f  // 1/sqrt(32)

typedef __attribute__((ext_vector_type(8))) short short8_t;
typedef __attribute__((ext_vector_type(4))) float floatx4;

static __device__ inline short f2bf(float f) {
  unsigned int u;
  __builtin_memcpy(&u, &f, 4);
  unsigned int r = (u + 0x7fffu + ((u >> 16) & 1u)) >> 16;
  return (short)r;
}
static __device__ inline float bf2f(short s) {
  unsigned int u = ((unsigned int)(unsigned short)s) << 16;
  float f;
  __builtin_memcpy(&f, &u, 4);
  return f;
}

// ---------------- wprep: weights + single-pass x->(xbf, ctxsum) + poff -----
__global__ void wprep(const float* __restrict__ x, const float* __restrict__ pos,
                      const float* __restrict__ w_val, const float* __restrict__ w_mem1v,
                      const float* __restrict__ w_off, const float* __restrict__ b_off,
                      const float* __restrict__ w_key, const float* __restrict__ w_gate,
                      const float* __restrict__ w_sk1, const float* __restrict__ w_out,
                      const float* __restrict__ w_sk2, const float* __restrict__ w_mem1o,
                      short* __restrict__ WA, short* __restrict__ W1,
                      short* __restrict__ WO, short* __restrict__ W2T,
                      short* __restrict__ W1OT,
                      short* __restrict__ xbf, float* __restrict__ poff,
                      float* __restrict__ ctxsum) {
  __shared__ float2 psum[2][128];
  int blk = blockIdx.x, tid = threadIdx.x;
  if (blk < 384) {
    int idx = blk * 256 + tid;
    int n = idx >> 8, k = idx & 255;
    float v;
    if (n < 256) v = w_val[k * 256 + n];
    else if (n < 288) v = w_mem1v[k * 32 + (n - 256)];
    else if (n < 320) v = w_off[k * 32 + (n - 288)];
    else if (n < 352) v = w_key[k * 32 + (n - 320)];
    else if (n == 352) v = w_gate[k];
    else v = 0.f;
    WA[idx] = f2bf(v);
  } else if (blk < 896) {
    int idx = (blk - 384) * 256 + tid;
    int n = idx >> 9, k = idx & 511;
    W1[idx] = f2bf(w_sk1[k * 256 + n]);
  } else if (blk < 1152) {
    int idx = (blk - 896) * 256 + tid;
    int n = idx >> 8, k = idx & 255;
    WO[idx] = f2bf(w_out[k * 256 + n]);
  } else if (blk < 1184) {
    int idx = (blk - 1152) * 256 + tid;  // p*256 + k
    int p = idx >> 8, k = idx & 255;
    W2T[idx] = f2bf(w_sk2[k * 32 + p]);
  } else if (blk < 1216) {
    int idx = (blk - 1184) * 256 + tid;  // d*32 + p
    int d = idx >> 5, p = idx & 31;
    W1OT[idx] = f2bf(w_mem1o[p * 256 + d]);
  } else if (blk < 1472) {
    int idx = (blk - 1216) * 256 + tid;
    int l = idx >> 5, p = idx & 31;
    float a = b_off[p];
#pragma unroll 8
    for (int j = 0; j < 32; ++j) a += pos[l * 32 + j] * w_off[(256 + j) * 32 + p];
    poff[idx] = a;
  } else {
    // single x pass: cast to xbf AND produce per-chunk d-sums (ctxsum)
    int c2 = blk - 1472;                 // 0..255 = (b, chunk)
    int b = c2 >> 6, ch = c2 & 63;
    int d2 = (tid & 127) * 2, h = tid >> 7;
    int tokb = b * L_ + ch * 32 + h * 16;
    float2 xv[16];
#pragma unroll
    for (int i = 0; i < 16; ++i)
      xv[i] = *(const float2*)&x[(tokb + i) * 256 + d2];
    float2 s = {0.f, 0.f};
#pragma unroll
    for (int i = 0; i < 16; ++i) { s.x += xv[i].x; s.y += xv[i].y; }
#pragma unroll
    for (int i = 0; i < 16; ++i) {
      short2 o;
      o.x = f2bf(xv[i].x);
      o.y = f2bf(xv[i].y);
      *(short2*)&xbf[(tokb + i) * 256 + d2] = o;
    }
    psum[h][tid & 127] = s;
    __syncthreads();
    if (h == 0) {
      float2 o = psum[1][tid & 127];
      float2 tot = {s.x + o.x, s.y + o.y};
      *(float2*)&ctxsum[c2 * 256 + d2] = tot;
    }
  }
}

// ---------------- gemmA3: fused gemm1 + A3 epilogue + ctx-prefix blocks ----
__global__ __launch_bounds__(768, 6) void gemmA3(const short* __restrict__ xbf,
                                                 const short* __restrict__ WA,
                                                 const float* __restrict__ pos,
                                                 const float* __restrict__ poff,
                                                 const float* __restrict__ b_mem1v,
                                                 const float* __restrict__ b_key,
                                                 const float* __restrict__ b_gate,
                                                 const float* __restrict__ b_val,
                                                 float* __restrict__ m1cT,
                                                 float* __restrict__ m1sT,
                                                 float* __restrict__ qc,
                                                 float* __restrict__ qs,
                                                 short* __restrict__ K2bf,
                                                 short* __restrict__ gvT,
                                                 float* __restrict__ sg,
                                                 float* __restrict__ ctxsum) {
  __shared__ float YL[16][132];  // cols 256..383 of Y, fp32
  __shared__ float gsh[16];
  int tid = threadIdx.x;
  int bc = blockIdx.x;
  if (bc >= 512) {
    // ctx-prefix: batch-8 loads, exclusive prefix over 64 chunks per (b,d)
    if (tid < 256) {
      int b = bc - 512;
      int base = b * 64 * 256 + tid;
      float run = 0.f;
      for (int c0 = 0; c0 < 64; c0 += 8) {
        float v[8];
#pragma unroll
        for (int j = 0; j < 8; ++j) v[j] = ctxsum[base + (c0 + j) * 256];
#pragma unroll
        for (int j = 0; j < 8; ++j) {
          ctxsum[base + (c0 + j) * 256] = run;
          run += v[j];
        }
      }
    }
    return;
  }
  int lane = tid & 63, w = tid >> 6;
  int ml = lane & 15, quad = lane >> 4, kq = quad * 8;
  int bc32 = bc >> 1, half = bc & 1;
  int tok0 = bc * 16;
  // prefetch epilogue operands (consumed after the barrier)
  float posv = 0.f, poffv = 0.f;
  if (tid < 512) {
    int t = tid >> 5, p = tid & 31;
    int l = (tok0 + t) & (L_ - 1);
    posv = pos[l * 32 + p];
    poffv = poff[l * 32 + p];
  }
  floatx4 acc[2] = {};
  const short* A0p = &xbf[(tok0 + ml) * 256 + kq];
  const short* Bp = &WA[(w * 32 + ml) * 256 + kq];
#pragma unroll
  for (int ks = 0; ks < 8; ++ks) {
    short8_t a0 = *(const short8_t*)(A0p + ks * 32);
#pragma unroll
    for (int nt = 0; nt < 2; ++nt) {
      short8_t b = *(const short8_t*)(Bp + nt * 16 * 256 + ks * 32);
      acc[nt] = __builtin_amdgcn_mfma_f32_16x16x32_bf16(a0, b, acc[nt], 0, 0, 0);
    }
  }
  // waves 8..11 stage cols 256..383 into LDS (fp32)
  if (w >= 8) {
#pragma unroll
    for (int nt = 0; nt < 2; ++nt) {
      int col = (w - 8) * 32 + nt * 16 + ml;
#pragma unroll
      for (int r = 0; r < 4; ++r)
        YL[quad * 4 + r][col] = acc[nt][r];
    }
  }
  __syncthreads();
  // A3 elementwise phase: 16 tok x 32 p = 512 items on threads 0..511
  if (tid < 512) {
    int t = tid >> 5, p = tid & 31;
    int tok = tok0 + t, l = tok & (L_ - 1);
    int b = tok >> 11;
    float v1 = YL[t][p] + b_mem1v[p];
    float pc = cosf(posv), ps = sinf(posv);
    int idxT = (b * 32 + p) * L_ + l;
    m1cT[idxT] = pc * v1;
    m1sT[idxT] = ps * v1;
    float off = tanhf(YL[t][32 + p] + poffv) * PI_F;
    float oc = cosf(off), os = sinf(off);
    int gidx = tok * 32 + p;
    qc[gidx] = pc * oc - ps * os;
    qs[gidx] = ps * oc + pc * os;
    float kp = tanhf(YL[t][64 + p] + b_key[p]) * PI_F;
    K2bf[tok * 64 + p] = f2bf(cosf(kp));
    K2bf[tok * 64 + 32 + p] = f2bf(sinf(kp));
    if (p == 0) {
      float g = 1.f / (1.f + expf(-(YL[t][96] + b_gate[0])));
      sg[tok] = g;
      gsh[t] = g;
    }
  }
  __syncthreads();
  // gvT = (values + b_val) * gate; waves 0..7 own d cols < 256
  if (w < 8) {
#pragma unroll
    for (int nt = 0; nt < 2; ++nt) {
      int d = w * 32 + nt * 16 + ml;
      float bv = b_val[d];
      int t0 = quad * 4;
      short4 o;
      o.x = f2bf((acc[nt][0] + bv) * gsh[t0 + 0]);
      o.y = f2bf((acc[nt][1] + bv) * gsh[t0 + 1]);
      o.z = f2bf((acc[nt][2] + bv) * gsh[t0 + 2]);
      o.w = f2bf((acc[nt][3] + bv) * gsh[t0 + 3]);
      *(short4*)&gvT[(bc32 * 256 + d) * 32 + half * 16 + t0] = o;
    }
  }
}

// ---------------- gemmCD: 512 blocks x 512 thr (2 blocks/CU) ---------------
// Block = (chunk cn, d-half dh). hs + SP duplicated across the dh pair
// (MFMA is ~3% util -> free); U covers only this block's d-half.
union __align__(16) CDMem {
  short As[32][520];                           // A tile [xbf | ctx], K=512
  struct { short HS[32][280]; short SPL[64][40]; } h;
};
__global__ __launch_bounds__(512, 4) void gemmCD(const short* __restrict__ xbf,
                                                 const float* __restrict__ x,
                                                 const float* __restrict__ ctxsum,
                                                 const short* __restrict__ W1,
                                                 const float* __restrict__ b_sk1,
                                                 const short* __restrict__ W2T,
                                                 const float* __restrict__ b_sk2,
                                                 const short* __restrict__ gvT,
                                                 short* __restrict__ SPbf,
                                                 short* __restrict__ UT) {
  __shared__ CDMem sm;
  __shared__ float stmp[256];
  int tid = threadIdx.x;
  int cn = blockIdx.x >> 1, dh = blockIdx.x & 1;
  int tok0 = cn * 32;
  int bI = cn >> 6, ch = cn & 63;
  int lane = tid & 63, w = tid >> 6;
  int ml = lane & 15, quad = lane >> 4, kq = quad * 8;
  // prefetch phase-C gvT B-frag for this d-half (consumed after 4 barriers)
  short8_t bgv = *(const short8_t*)&gvT[(cn * 256 + dh * 128 + w * 16 + ml) * 32 + kq];
  // stage xbf (cols 0..255): two short8 per thread
#pragma unroll
  for (int pass = 0; pass < 2; ++pass) {
    int idx = pass * 512 + tid;
    int row = idx >> 5, c8 = idx & 31;
    *(short8_t*)&sm.As[row][c8 * 8] =
        *(const short8_t*)&xbf[(tok0 + row) * 256 + c8 * 8];
  }
  // ctx (cols 256..511): prefix is ONE load (prescanned); 2 token-halves
  {
    int d = tid & 255, qh = tid >> 8;
    float cp = ctxsum[(bI * 64 + ch) * 256 + d];  // exclusive chunk prefix
    float xv[16];
    int xb = (tok0 + qh * 16) * 256 + d;
#pragma unroll
    for (int i = 0; i < 16; ++i) xv[i] = x[xb + i * 256];
    if (qh == 0) {
      float p = 0.f;
#pragma unroll
      for (int i = 0; i < 16; ++i) p += xv[i];
      stmp[d] = p;
    }
    __syncthreads();  // barrier 1
    float run = cp + (qh ? stmp[d] : 0.f);
    int l0 = ch * 32 + qh * 16;
#pragma unroll
    for (int i = 0; i < 16; ++i) {
      run += xv[i];
      sm.As[qh * 16 + i][256 + d] = f2bf(run / (float)(l0 + i + 1));
    }
  }
  __syncthreads();  // barrier 2: full A tile ready
  // hs = gelu(A @ W1 + b_sk1); wave w owns n-cols [w*32, w*32+32)
  int n0w = w * 32;
  floatx4 acc[2][2] = {};
#pragma unroll
  for (int kt = 0; kt < 16; ++kt) {
    short8_t a0 = *(short8_t*)&sm.As[ml][kt * 32 + kq];
    short8_t a1 = *(short8_t*)&sm.As[16 + ml][kt * 32 + kq];
    short8_t b0 = *(const short8_t*)&W1[(n0w + ml) * 512 + kt * 32 + kq];
    short8_t b1 = *(const short8_t*)&W1[(n0w + 16 + ml) * 512 + kt * 32 + kq];
    acc[0][0] = __builtin_amdgcn_mfma_f32_16x16x32_bf16(a0, b0, acc[0][0], 0, 0, 0);
    acc[0][1] = __builtin_amdgcn_mfma_f32_16x16x32_bf16(a0, b1, acc[0][1], 0, 0, 0);
    acc[1][0] = __builtin_amdgcn_mfma_f32_16x16x32_bf16(a1, b0, acc[1][0], 0, 0, 0);
    acc[1][1] = __builtin_amdgcn_mfma_f32_16x16x32_bf16(a1, b1, acc[1][1], 0, 0, 0);
  }
  short hv[2][2][4];
#pragma unroll
  for (int nt = 0; nt < 2; ++nt) {
    float bv = b_sk1[n0w + nt * 16 + ml];
#pragma unroll
    for (int mt = 0; mt < 2; ++mt)
#pragma unroll
      for (int r = 0; r < 4; ++r) {
        float v = acc[mt][nt][r] + bv;
        float g = 0.5f * v * (1.f + erff(v * 0.70710678118654752f));
        hv[mt][nt][r] = f2bf(g);
      }
  }
  __syncthreads();  // barrier 3: As dead; HS aliases it
#pragma unroll
  for (int mt = 0; mt < 2; ++mt)
#pragma unroll
    for (int nt = 0; nt < 2; ++nt)
#pragma unroll
      for (int r = 0; r < 4; ++r)
        sm.h.HS[mt * 16 + quad * 4 + r][n0w + nt * 16 + ml] = hv[mt][nt][r];
  __syncthreads();  // barrier 4: HS ready
  // SP = tanh(hs @ W2T + b_sk2)*pi (waves 0..3; duplicated across dh pair)
  if (w < 4) {
    int th = w & 1, ph = w >> 1;
    floatx4 pacc = {};
#pragma unroll
    for (int s = 0; s < 8; ++s) {
      short8_t a = *(short8_t*)&sm.h.HS[th * 16 + ml][s * 32 + kq];
      short8_t b0 = *(const short8_t*)&W2T[(ph * 16 + ml) * 256 + s * 32 + kq];
      pacc = __builtin_amdgcn_mfma_f32_16x16x32_bf16(a, b0, pacc, 0, 0, 0);
    }
    int p = ph * 16 + ml;
    float bs = b_sk2[p];
#pragma unroll
    for (int r = 0; r < 4; ++r) {
      int tl = th * 16 + quad * 4 + r;
      int tok = tok0 + tl;
      float sp = tanhf(pacc[r] + bs) * PI_F;
      short c = f2bf(cosf(sp)), s2 = f2bf(sinf(sp));
      sm.h.SPL[p][tl] = c;
      sm.h.SPL[32 + p][tl] = s2;
      if (dh == 0) {
        SPbf[tok * 64 + p] = c;
        SPbf[tok * 64 + 32 + p] = s2;
      }
    }
  }
  __syncthreads();  // barrier 5: SPL ready
  // Phase C: U chunk sums; wave w owns d in [dh*128 + w*16, +16)
  short8_t a[4];
#pragma unroll
  for (int mt = 0; mt < 4; ++mt) a[mt] = *(short8_t*)&sm.h.SPL[mt * 16 + ml][kq];
  floatx4 acc3[4] = {};
#pragma unroll
  for (int mt = 0; mt < 4; ++mt)
    acc3[mt] = __builtin_amdgcn_mfma_f32_16x16x32_bf16(a[mt], bgv, acc3[mt], 0, 0, 0);
  {
    int d = dh * 128 + w * 16 + ml;
#pragma unroll
    for (int mt = 0; mt < 4; ++mt) {
      short4 o;
      o.x = f2bf(acc3[mt][0]);
      o.y = f2bf(acc3[mt][1]);
      o.z = f2bf(acc3[mt][2]);
      o.w = f2bf(acc3[mt][3]);
      *(short4*)&UT[(cn * 256 + d) * 64 + mt * 16 + quad * 4] = o;
    }
  }
}

// ---------------- scanE: m1/sg token scans + UT chunk prefix (merged) ------
__global__ void scanE(float* __restrict__ m1cT, float* __restrict__ m1sT,
                      float* __restrict__ sg, short* __restrict__ UT) {
  __shared__ float wsum[4];
  __shared__ float stot[4][64];
  int blk = blockIdx.x;
  int tid = threadIdx.x;
  if (blk >= 260) {
    int eb = blk - 260;               // 0..1023
    int w = tid >> 6, lane = tid & 63;
    int pi = eb * 64 + lane;          // 64 consecutive pi per block
    int q = pi & 63;
    int d = (pi >> 6) & 255;
    int b = pi >> 14;
    const int cs = 256 * 64;
    int base = ((b * NC) * 256 + d) * 64 + q;
    short v[16];
#pragma unroll
    for (int c = 0; c < 16; ++c) v[c] = UT[base + (w * 16 + c) * cs];
    float tot = 0.f;
#pragma unroll
    for (int c = 0; c < 16; ++c) tot += bf2f(v[c]);
    stot[w][lane] = tot;
    __syncthreads();
    float run = 0.f;
    for (int ww = 0; ww < w; ++ww) run += stot[ww][lane];
#pragma unroll
    for (int c = 0; c < 16; ++c) {
      UT[base + (w * 16 + c) * cs] = f2bf(run);
      run += bf2f(v[c]);
    }
    return;
  }
  int lane = tid & 63, w = tid >> 6;
  float* arr;
  int base;
  if (blk < 256) {
    arr = (blk < 128) ? m1cT : m1sT;
    base = (blk & 127) * L_;
  } else {
    arr = sg;
    base = (blk - 256) * L_;
  }
  int sbase = base + w * 512;
  float v[8];
#pragma unroll
  for (int i = 0; i < 8; ++i) v[i] = arr[sbase + i * 64 + lane];
  float carry = 0.f;
#pragma unroll
  for (int i = 0; i < 8; ++i) {
    float vv = v[i];
#pragma unroll
    for (int off = 1; off < 64; off <<= 1) {
      float n = __shfl_up(vv, off, 64);
      if (lane >= off) vv += n;
    }
    vv += carry;
    v[i] = vv;
    carry = __shfl(vv, 63, 64);
  }
  if (lane == 0) wsum[w] = carry;
  __syncthreads();
  float off = 0.f;
  for (int ww = 0; ww < w; ++ww) off += wsum[ww];
#pragma unroll
  for (int i = 0; i < 8; ++i) arr[sbase + i * 64 + lane] = v[i] + off;
}

// ---------------- fgOut: 512 blocks x 512 thr (2 blocks/CU) ----------------
// Block = (chunk cn, token-half th). Wave w owns 32 d-cols. Retrieval +
// pos_out + LN + gemm2 + coalesced epilogue for its 16 tokens.
struct __align__(16) FGMem {
  short SL[16][40];
  short PR[16][40];
  float CMB[16][260];
  short CBN[16][280];
  float LG[256], LB[256];
  float scl[16], mu_s[16], rs_s[16];
};
__global__ __launch_bounds__(512, 4) void fgOut(const short* __restrict__ UT,
                                                const short* __restrict__ SPbf,
                                                const short* __restrict__ K2bf,
                                                const short* __restrict__ gvT,
                                                const float* __restrict__ sgc,
                                                const float* __restrict__ m1cT,
                                                const float* __restrict__ m1sT,
                                                const float* __restrict__ qc,
                                                const float* __restrict__ qs,
                                                const short* __restrict__ W1OT,
                                                const float* __restrict__ b_mem1o,
                                                const float* __restrict__ ln_g,
                                                const float* __restrict__ ln_b,
                                                const short* __restrict__ WO,
                                                const float* __restrict__ b_out,
                                                const float* __restrict__ x,
                                                float* __restrict__ out) {
  __shared__ FGMem sm;
  int tid = threadIdx.x;
  int cn = blockIdx.x >> 1, th = blockIdx.x & 1;
  int lbase = cn * CL;
  int tb = lbase + th * 16;            // this block's first token
  int bb = cn >> 6, lloc = (cn & 63) * 32;
  int lane = tid & 63, w = tid >> 6;
  int ml = lane & 15, quad = lane >> 4, kq = quad * 8;
  int d0 = w * 32;
  // ---- entry prefetches (consumed after barriers; hide HBM latency) ----
  short8_t ub[2][2], gvb[2], w1b[2];
#pragma unroll
  for (int nt = 0; nt < 2; ++nt) {
    int d = d0 + nt * 16 + ml;
    ub[nt][0] = *(const short8_t*)&UT[(cn * 256 + d) * 64 + kq];
    ub[nt][1] = *(const short8_t*)&UT[(cn * 256 + d) * 64 + 32 + kq];
    gvb[nt] = *(const short8_t*)&gvT[(cn * 256 + d) * 32 + kq];
    w1b[nt] = *(const short8_t*)&W1OT[d * 32 + kq];
  }
  const float4* x4 = (const float4*)&x[tb * 256];
  float4 xp0 = x4[tid];
  float4 xp1 = x4[tid + 512];
  if (tid < 16) sm.scl[tid] = rsqrtf(fmaxf(sgc[tb + tid], 1.f)) * INV_SQRT_P;
  if (tid >= 256) {
    int d = tid - 256;
    sm.LG[d] = ln_g[d];
    sm.LB[d] = ln_b[d];
  }
  // K2 frags for this block's 16 token rows
  short8_t ka0 = *(const short8_t*)&K2bf[(tb + ml) * 64 + kq];
  short8_t kb0 = *(const short8_t*)&K2bf[(tb + ml) * 64 + 32 + kq];
  if (w == 0) {
    // S = K2 @ SP^T (16 rows x 32 cols), causal mask, write SL
    floatx4 sacc[2] = {};
#pragma unroll
    for (int ks2 = 0; ks2 < 2; ++ks2) {
      short8_t a = (ks2 == 0) ? ka0 : kb0;
      short8_t b0 = *(const short8_t*)&SPbf[(lbase + ml) * 64 + ks2 * 32 + kq];
      short8_t b1 = *(const short8_t*)&SPbf[(lbase + 16 + ml) * 64 + ks2 * 32 + kq];
      sacc[0] = __builtin_amdgcn_mfma_f32_16x16x32_bf16(a, b0, sacc[0], 0, 0, 0);
      sacc[1] = __builtin_amdgcn_mfma_f32_16x16x32_bf16(a, b1, sacc[1], 0, 0, 0);
    }
#pragma unroll
    for (int nt = 0; nt < 2; ++nt)
#pragma unroll
      for (int r = 0; r < 4; ++r) {
        int trowL = quad * 4 + r;               // local row 0..15
        int tl = th * 16 + trowL;               // chunk-local token
        int scol = nt * 16 + ml;
        float v = (scol <= tl) ? sacc[nt][r] : 0.f;
        sm.SL[trowL][scol] = f2bf(v);
      }
  } else {
    // PR prep: 16 tok x 32 p = 512 items over 448 threads (waves 1-7)
    for (int i = tid - 64; i < 512; i += 448) {
      int pp = i >> 4, t16 = i & 15;
      int gT = (bb * 32 + pp) * L_ + lloc + th * 16 + t16;
      int g = (tb + t16) * 32 + pp;
      sm.PR[t16][pp] = f2bf((m1cT[gT] * qc[g] + m1sT[gT] * qs[g]) * INV_SQRT_P);
    }
  }
  __syncthreads();
  // Part 1: K2 @ Uprev (both k-halves); B-frags prefetched
  floatx4 acc[2] = {};
#pragma unroll
  for (int nt = 0; nt < 2; ++nt) {
    acc[nt] = __builtin_amdgcn_mfma_f32_16x16x32_bf16(ka0, ub[nt][0], acc[nt], 0, 0, 0);
    acc[nt] = __builtin_amdgcn_mfma_f32_16x16x32_bf16(kb0, ub[nt][1], acc[nt], 0, 0, 0);
  }
  // Part 2: S @ gv
  {
    short8_t a0 = *(short8_t*)&sm.SL[ml][kq];
#pragma unroll
    for (int nt = 0; nt < 2; ++nt)
      acc[nt] = __builtin_amdgcn_mfma_f32_16x16x32_bf16(a0, gvb[nt], acc[nt], 0, 0, 0);
  }
  // pos_out MFMA
  floatx4 macc[2] = {};
  {
    short8_t a0 = *(short8_t*)&sm.PR[ml][kq];
#pragma unroll
    for (int nt = 0; nt < 2; ++nt)
      macc[nt] = __builtin_amdgcn_mfma_f32_16x16x32_bf16(a0, w1b[nt], macc[nt], 0, 0, 0);
  }
#pragma unroll
  for (int nt = 0; nt < 2; ++nt) {
    int d = d0 + nt * 16 + ml;
    float bm = b_mem1o[d];
#pragma unroll
    for (int r = 0; r < 4; ++r) {
      int t16 = quad * 4 + r;
      sm.CMB[t16][d] = acc[nt][r] * sm.scl[t16] + macc[nt][r] + bm;
    }
  }
  __syncthreads();
  // LN stats: 32 threads per token, 8 elements each
  {
    int t16 = tid >> 5, g = tid & 31;
    float s = 0.f, s2 = 0.f;
#pragma unroll
    for (int j = 0; j < 8; ++j) {
      float v = sm.CMB[t16][g + j * 32];
      s += v;
      s2 += v * v;
    }
#pragma unroll
    for (int m = 1; m < 32; m <<= 1) {
      s += __shfl_xor(s, m, 64);
      s2 += __shfl_xor(s2, m, 64);
    }
    if (g == 0) {
      float mu = s / (float)D_;
      float var = s2 / (float)D_ - mu * mu;
      sm.mu_s[t16] = mu;
      sm.rs_s[t16] = rsqrtf(var + 1e-5f);
    }
  }
  __syncthreads();
  // normalize -> CBN (bf16) in LDS: 16x256 = 4096 / 512 = 8 per thread
#pragma unroll
  for (int it = 0; it < 8; ++it) {
    int i = it * 512 + tid;
    int t16 = i >> 8, d = i & 255;
    sm.CBN[t16][d] = f2bf((sm.CMB[t16][d] - sm.mu_s[t16]) * sm.rs_s[t16] * sm.LG[d] + sm.LB[d]);
  }
  __syncthreads();
  // gemm2: CBN @ WO + b_out -> CMB (reuse)
  floatx4 acc2[2] = {};
#pragma unroll
  for (int kt = 0; kt < 8; ++kt) {
    short8_t a0 = *(short8_t*)&sm.CBN[ml][kt * 32 + kq];
#pragma unroll
    for (int nt = 0; nt < 2; ++nt) {
      short8_t b = *(const short8_t*)&WO[(d0 + nt * 16 + ml) * 256 + kt * 32 + kq];
      acc2[nt] = __builtin_amdgcn_mfma_f32_16x16x32_bf16(a0, b, acc2[nt], 0, 0, 0);
    }
  }
#pragma unroll
  for (int nt = 0; nt < 2; ++nt) {
    int n = d0 + nt * 16 + ml;
    float bv = b_out[n];
#pragma unroll
    for (int r = 0; r < 4; ++r) {
      int t16 = quad * 4 + r;
      sm.CMB[t16][n] = acc2[nt][r] + bv;
    }
  }
  __syncthreads();
  // coalesced float4 epilogue: out = x + CMB
  {
    float4* o4 = (float4*)&out[tb * 256];
#pragma unroll
    for (int k = 0; k < 2; ++k) {
      int idx4 = tid + k * 512;
      int t16 = idx4 >> 6, dd = (idx4 & 63) * 4;
      float4 xp = (k == 0) ? xp0 : xp1;
      float4 o;
      o.x = xp.x + sm.CMB[t16][dd + 0];
      o.y = xp.y + sm.CMB[t16][dd + 1];
      o.z = xp.z + sm.CMB[t16][dd + 2];
      o.w = xp.w + sm.CMB[t16][dd + 3];
      o4[idx4] = o;
    }
  }
}

extern "C" void kernel_launch(void* const* d_in, const int* in_sizes, int n_in,
                              void* d_out, int out_size, void* d_ws, size_t ws_size,
                              hipStream_t stream) {
  const float* x = (const float*)d_in[0];
  const float* pos = (const float*)d_in[1];
  const float* w_mem1v = (const float*)d_in[2];
  const float* b_mem1v = (const float*)d_in[3];
  const float* w_mem1o = (const float*)d_in[4];
  const float* b_mem1o = (const float*)d_in[5];
  const float* w_off = (const float*)d_in[6];
  const float* b_off = (const float*)d_in[7];
  const float* w_key = (const float*)d_in[8];
  const float* b_key = (const float*)d_in[9];
  const float* w_val = (const float*)d_in[10];
  const float* b_val = (const float*)d_in[11];
  const float* w_sk1 = (const float*)d_in[12];
  const float* b_sk1 = (const float*)d_in[13];
  const float* w_sk2 = (const float*)d_in[14];
  const float* b_sk2 = (const float*)d_in[15];
  const float* w_gate = (const float*)d_in[16];
  const float* b_gate = (const float*)d_in[17];
  const float* ln_g = (const float*)d_in[18];
  const float* ln_b = (const float*)d_in[19];
  const float* w_out = (const float*)d_in[20];
  const float* b_out = (const float*)d_in[21];
  float* out = (float*)d_out;
  float* ws = (float*)d_ws;

  const int BLP = B_ * L_ * P_;  // 262144
  const int BLD = B_ * L_ * D_;  // 2097152
  float* m1cT = ws;
  float* m1sT = m1cT + BLP;
  float* qc = m1sT + BLP;
  float* qs = qc + BLP;
  float* sg = qs + BLP;
  float* poff = sg + B_ * L_;
  float* ctxsum = poff + L_ * P_;              // B*64*256 = 65536 floats
  short* UT = (short*)(ctxsum + B_ * 64 * 256);
  short* xbf = UT + (size_t)B_ * NC * 256 * 64;
  short* ctxbf = xbf + BLD;           // unused (layout stability)
  short* hs = ctxbf + BLD;            // unused (layout stability)
  short* gvT = hs + BLD;
  short* K2bf = gvT + BLD;            // B*L*64
  short* SPbf = K2bf + B_ * L_ * 64;  // B*L*64
  short* WA = SPbf + B_ * L_ * 64;
  short* W1 = WA + 384 * 256;
  short* WO = W1 + 256 * 512;
  short* W2T = WO + 256 * 256;
  short* W1OT = W2T + 32 * 256;

  wprep<<<1728, 256, 0, stream>>>(x, pos, w_val, w_mem1v, w_off, b_off, w_key, w_gate,
                                  w_sk1, w_out, w_sk2, w_mem1o, WA, W1, WO, W2T, W1OT,
                                  xbf, poff, ctxsum);
  gemmA3<<<516, 768, 0, stream>>>(xbf, WA, pos, poff, b_mem1v, b_key, b_gate, b_val,
                                  m1cT, m1sT, qc, qs, K2bf, gvT, sg, ctxsum);
  gemmCD<<<512, 512, 0, stream>>>(xbf, x, ctxsum, W1, b_sk1, W2T, b_sk2, gvT, SPbf, UT);
  scanE<<<1284, 256, 0, stream>>>(m1cT, m1sT, sg, UT);
  fgOut<<<512, 512, 0, stream>>>(UT, SPbf, K2bf, gvT, sg, m1cT, m1sT, qc, qs,
                                 W1OT, b_mem1o, ln_g, ln_b, WO, b_out, x, out);
}

// Round 12
// 161.643 us; speedup vs baseline: 1.0705x; 1.0705x over previous
//
#include <hip/hip_runtime.h>
#include <hip/hip_bf16.h>

constexpr int B_ = 4;
constexpr int L_ = 2048;
constexpr int D_ = 256;
constexpr int P_ = 32;
constexpr int CL = 32;   // chunk length for KV scan
constexpr int NC = L_ / CL;  // 64 chunks

#define PI_F 3.14159265358979323846f
#define INV_SQRT_P 0.17677669529663687f  // 1/sqrt(32)

typedef __attribute__((ext_vector_type(8))) short short8_t;
typedef __attribute__((ext_vector_type(4))) float floatx4;

static __device__ inline short f2bf(float f) {
  unsigned int u;
  __builtin_memcpy(&u, &f, 4);
  unsigned int r = (u + 0x7fffu + ((u >> 16) & 1u)) >> 16;
  return (short)r;
}
static __device__ inline float bf2f(short s) {
  unsigned int u = ((unsigned int)(unsigned short)s) << 16;
  float f;
  __builtin_memcpy(&f, &u, 4);
  return f;
}

// ---------------- wprep: weights + single-pass x->(xbf, ctxsum) + poff -----
__global__ void wprep(const float* __restrict__ x, const float* __restrict__ pos,
                      const float* __restrict__ w_val, const float* __restrict__ w_mem1v,
                      const float* __restrict__ w_off, const float* __restrict__ b_off,
                      const float* __restrict__ w_key, const float* __restrict__ w_gate,
                      const float* __restrict__ w_sk1, const float* __restrict__ w_out,
                      const float* __restrict__ w_sk2, const float* __restrict__ w_mem1o,
                      short* __restrict__ WA, short* __restrict__ W1,
                      short* __restrict__ WO, short* __restrict__ W2T,
                      short* __restrict__ W1OT,
                      short* __restrict__ xbf, float* __restrict__ poff,
                      float* __restrict__ ctxsum) {
  __shared__ float2 psum[2][128];
  int blk = blockIdx.x, tid = threadIdx.x;
  if (blk < 384) {
    int idx = blk * 256 + tid;
    int n = idx >> 8, k = idx & 255;
    float v;
    if (n < 256) v = w_val[k * 256 + n];
    else if (n < 288) v = w_mem1v[k * 32 + (n - 256)];
    else if (n < 320) v = w_off[k * 32 + (n - 288)];
    else if (n < 352) v = w_key[k * 32 + (n - 320)];
    else if (n == 352) v = w_gate[k];
    else v = 0.f;
    WA[idx] = f2bf(v);
  } else if (blk < 896) {
    int idx = (blk - 384) * 256 + tid;
    int n = idx >> 9, k = idx & 511;
    W1[idx] = f2bf(w_sk1[k * 256 + n]);
  } else if (blk < 1152) {
    int idx = (blk - 896) * 256 + tid;
    int n = idx >> 8, k = idx & 255;
    WO[idx] = f2bf(w_out[k * 256 + n]);
  } else if (blk < 1184) {
    int idx = (blk - 1152) * 256 + tid;  // p*256 + k
    int p = idx >> 8, k = idx & 255;
    W2T[idx] = f2bf(w_sk2[k * 32 + p]);
  } else if (blk < 1216) {
    int idx = (blk - 1184) * 256 + tid;  // d*32 + p
    int d = idx >> 5, p = idx & 31;
    W1OT[idx] = f2bf(w_mem1o[p * 256 + d]);
  } else if (blk < 1472) {
    int idx = (blk - 1216) * 256 + tid;
    int l = idx >> 5, p = idx & 31;
    float a = b_off[p];
#pragma unroll 8
    for (int j = 0; j < 32; ++j) a += pos[l * 32 + j] * w_off[(256 + j) * 32 + p];
    poff[idx] = a;
  } else {
    // single x pass: cast to xbf AND produce per-chunk d-sums (ctxsum)
    int c2 = blk - 1472;                 // 0..255 = (b, chunk)
    int b = c2 >> 6, ch = c2 & 63;
    int d2 = (tid & 127) * 2, h = tid >> 7;
    int tokb = b * L_ + ch * 32 + h * 16;
    float2 xv[16];
#pragma unroll
    for (int i = 0; i < 16; ++i)
      xv[i] = *(const float2*)&x[(tokb + i) * 256 + d2];
    float2 s = {0.f, 0.f};
#pragma unroll
    for (int i = 0; i < 16; ++i) { s.x += xv[i].x; s.y += xv[i].y; }
#pragma unroll
    for (int i = 0; i < 16; ++i) {
      short2 o;
      o.x = f2bf(xv[i].x);
      o.y = f2bf(xv[i].y);
      *(short2*)&xbf[(tokb + i) * 256 + d2] = o;
    }
    psum[h][tid & 127] = s;
    __syncthreads();
    if (h == 0) {
      float2 o = psum[1][tid & 127];
      float2 tot = {s.x + o.x, s.y + o.y};
      *(float2*)&ctxsum[c2 * 256 + d2] = tot;
    }
  }
}

// ---------------- gemmA3: fused gemm1 + A3 epilogue + ctx-prefix blocks ----
__global__ __launch_bounds__(768, 6) void gemmA3(const short* __restrict__ xbf,
                                                 const short* __restrict__ WA,
                                                 const float* __restrict__ pos,
                                                 const float* __restrict__ poff,
                                                 const float* __restrict__ b_mem1v,
                                                 const float* __restrict__ b_key,
                                                 const float* __restrict__ b_gate,
                                                 const float* __restrict__ b_val,
                                                 float* __restrict__ m1cT,
                                                 float* __restrict__ m1sT,
                                                 float* __restrict__ qc,
                                                 float* __restrict__ qs,
                                                 short* __restrict__ K2bf,
                                                 short* __restrict__ gvT,
                                                 float* __restrict__ sg,
                                                 float* __restrict__ ctxsum) {
  __shared__ float YL[16][132];  // cols 256..383 of Y, fp32
  __shared__ float gsh[16];
  int tid = threadIdx.x;
  int bc = blockIdx.x;
  if (bc >= 512) {
    // ctx-prefix: batch-8 loads, exclusive prefix over 64 chunks per (b,d)
    if (tid < 256) {
      int b = bc - 512;
      int base = b * 64 * 256 + tid;
      float run = 0.f;
      for (int c0 = 0; c0 < 64; c0 += 8) {
        float v[8];
#pragma unroll
        for (int j = 0; j < 8; ++j) v[j] = ctxsum[base + (c0 + j) * 256];
#pragma unroll
        for (int j = 0; j < 8; ++j) {
          ctxsum[base + (c0 + j) * 256] = run;
          run += v[j];
        }
      }
    }
    return;
  }
  int lane = tid & 63, w = tid >> 6;
  int ml = lane & 15, quad = lane >> 4, kq = quad * 8;
  int bc32 = bc >> 1, half = bc & 1;
  int tok0 = bc * 16;
  // prefetch epilogue operands (consumed after the barrier; hides latency
  // under the MFMA loop)
  float posv = 0.f, poffv = 0.f;
  if (tid < 512) {
    int t = tid >> 5, p = tid & 31;
    int l = (tok0 + t) & (L_ - 1);
    posv = pos[l * 32 + p];
    poffv = poff[l * 32 + p];
  }
  floatx4 acc[2] = {};
  const short* A0p = &xbf[(tok0 + ml) * 256 + kq];
  const short* Bp = &WA[(w * 32 + ml) * 256 + kq];
#pragma unroll
  for (int ks = 0; ks < 8; ++ks) {
    short8_t a0 = *(const short8_t*)(A0p + ks * 32);
#pragma unroll
    for (int nt = 0; nt < 2; ++nt) {
      short8_t b = *(const short8_t*)(Bp + nt * 16 * 256 + ks * 32);
      acc[nt] = __builtin_amdgcn_mfma_f32_16x16x32_bf16(a0, b, acc[nt], 0, 0, 0);
    }
  }
  // waves 8..11 stage cols 256..383 into LDS (fp32)
  if (w >= 8) {
#pragma unroll
    for (int nt = 0; nt < 2; ++nt) {
      int col = (w - 8) * 32 + nt * 16 + ml;
#pragma unroll
      for (int r = 0; r < 4; ++r)
        YL[quad * 4 + r][col] = acc[nt][r];
    }
  }
  __syncthreads();
  // A3 elementwise phase: 16 tok x 32 p = 512 items on threads 0..511
  if (tid < 512) {
    int t = tid >> 5, p = tid & 31;
    int tok = tok0 + t, l = tok & (L_ - 1);
    int b = tok >> 11;
    float v1 = YL[t][p] + b_mem1v[p];
    float pc = cosf(posv), ps = sinf(posv);
    int idxT = (b * 32 + p) * L_ + l;
    m1cT[idxT] = pc * v1;
    m1sT[idxT] = ps * v1;
    float off = tanhf(YL[t][32 + p] + poffv) * PI_F;
    float oc = cosf(off), os = sinf(off);
    int gidx = tok * 32 + p;
    qc[gidx] = pc * oc - ps * os;
    qs[gidx] = ps * oc + pc * os;
    float kp = tanhf(YL[t][64 + p] + b_key[p]) * PI_F;
    K2bf[tok * 64 + p] = f2bf(cosf(kp));
    K2bf[tok * 64 + 32 + p] = f2bf(sinf(kp));
    if (p == 0) {
      float g = 1.f / (1.f + expf(-(YL[t][96] + b_gate[0])));
      sg[tok] = g;
      gsh[t] = g;
    }
  }
  __syncthreads();
  // gvT = (values + b_val) * gate; waves 0..7 own d cols < 256
  if (w < 8) {
#pragma unroll
    for (int nt = 0; nt < 2; ++nt) {
      int d = w * 32 + nt * 16 + ml;
      float bv = b_val[d];
      int t0 = quad * 4;
      short4 o;
      o.x = f2bf((acc[nt][0] + bv) * gsh[t0 + 0]);
      o.y = f2bf((acc[nt][1] + bv) * gsh[t0 + 1]);
      o.z = f2bf((acc[nt][2] + bv) * gsh[t0 + 2]);
      o.w = f2bf((acc[nt][3] + bv) * gsh[t0 + 3]);
      *(short4*)&gvT[(bc32 * 256 + d) * 32 + half * 16 + t0] = o;
    }
  }
}

// ---------------- gemmCD: ctx-in-LDS + gemm1 (hs in LDS) + kernelCD --------
union __align__(16) CDMem {
  short As[32][520];                           // A tile [xbf | ctx], K=512
  struct { short HS[32][280]; short SPL[64][40]; } h;
};
__global__ __launch_bounds__(1024, 4) void gemmCD(const short* __restrict__ xbf,
                                                  const float* __restrict__ x,
                                                  const float* __restrict__ ctxsum,
                                                  const short* __restrict__ W1,
                                                  const float* __restrict__ b_sk1,
                                                  const short* __restrict__ W2T,
                                                  const float* __restrict__ b_sk2,
                                                  const short* __restrict__ gvT,
                                                  short* __restrict__ SPbf,
                                                  short* __restrict__ UT) {
  __shared__ CDMem sm;
  __shared__ float stmp[4][256];
  int tid = threadIdx.x;
  int bc = blockIdx.x;
  int tok0 = bc * 32;
  int bI = bc >> 6, ch = bc & 63;
  int lane = tid & 63, w = tid >> 6;
  int ml = lane & 15, quad = lane >> 4, kq = quad * 8;
  // prefetch phase-C gvT B-frag (consumed after 4 barriers; hides HBM latency)
  short8_t bgv = *(const short8_t*)&gvT[(bc * 256 + w * 16 + ml) * 32 + kq];
  // stage xbf half of A (cols 0..255): 1024 short8, one per thread
  {
    int row = tid >> 5, c8 = tid & 31;
    *(short8_t*)&sm.As[row][c8 * 8] =
        *(const short8_t*)&xbf[(tok0 + row) * 256 + c8 * 8];
  }
  // ctx half (cols 256..511): prefix is ONE load; 4 token-quarters
  {
    int d = tid & 255, qh = tid >> 8;
    float cp = ctxsum[(bI * 64 + ch) * 256 + d];  // exclusive chunk prefix
    float xv[8];
    int xb = (tok0 + qh * 8) * 256 + d;
#pragma unroll
    for (int i = 0; i < 8; ++i) xv[i] = x[xb + i * 256];
    float p = 0.f;
#pragma unroll
    for (int i = 0; i < 8; ++i) p += xv[i];
    stmp[qh][d] = p;
    __syncthreads();
    float run = cp;
    for (int j = 0; j < qh; ++j) run += stmp[j][d];
    int l0 = ch * 32 + qh * 8;
#pragma unroll
    for (int i = 0; i < 8; ++i) {
      run += xv[i];
      sm.As[qh * 8 + i][256 + d] = f2bf(run / (float)(l0 + i + 1));
    }
  }
  __syncthreads();
  // hs = gelu(A @ W1 + b_sk1); wave w owns n-cols [w*16, w*16+16)
  int n0w = w * 16;
  floatx4 acc[2] = {};
#pragma unroll
  for (int kt = 0; kt < 16; ++kt) {
    short8_t a0 = *(short8_t*)&sm.As[ml][kt * 32 + kq];
    short8_t a1 = *(short8_t*)&sm.As[16 + ml][kt * 32 + kq];
    short8_t b0 = *(const short8_t*)&W1[(n0w + ml) * 512 + kt * 32 + kq];
    acc[0] = __builtin_amdgcn_mfma_f32_16x16x32_bf16(a0, b0, acc[0], 0, 0, 0);
    acc[1] = __builtin_amdgcn_mfma_f32_16x16x32_bf16(a1, b0, acc[1], 0, 0, 0);
  }
  short hv[2][4];
  {
    float bv = b_sk1[n0w + ml];
#pragma unroll
    for (int mt = 0; mt < 2; ++mt)
#pragma unroll
      for (int r = 0; r < 4; ++r) {
        float v = acc[mt][r] + bv;
        float g = 0.5f * v * (1.f + erff(v * 0.70710678118654752f));
        hv[mt][r] = f2bf(g);
      }
  }
  __syncthreads();  // As dead; HS aliases it
#pragma unroll
  for (int mt = 0; mt < 2; ++mt)
#pragma unroll
    for (int r = 0; r < 4; ++r)
      sm.h.HS[mt * 16 + quad * 4 + r][n0w + ml] = hv[mt][r];
  __syncthreads();
  // Phase B (waves 0..3): SP = tanh(hs @ W2T + b_sk2)*pi -> SPL + SPbf
  if (w < 4) {
    int th = w & 1, ph = w >> 1;
    floatx4 pacc = {};
#pragma unroll
    for (int s = 0; s < 8; ++s) {
      short8_t a = *(short8_t*)&sm.h.HS[th * 16 + ml][s * 32 + kq];
      short8_t b0 = *(const short8_t*)&W2T[(ph * 16 + ml) * 256 + s * 32 + kq];
      pacc = __builtin_amdgcn_mfma_f32_16x16x32_bf16(a, b0, pacc, 0, 0, 0);
    }
    int p = ph * 16 + ml;
    float bs = b_sk2[p];
#pragma unroll
    for (int r = 0; r < 4; ++r) {
      int tl = th * 16 + quad * 4 + r;
      int tok = tok0 + tl;
      float sp = tanhf(pacc[r] + bs) * PI_F;
      short c = f2bf(cosf(sp)), s2 = f2bf(sinf(sp));
      sm.h.SPL[p][tl] = c;
      sm.h.SPL[32 + p][tl] = s2;
      SPbf[tok * 64 + p] = c;
      SPbf[tok * 64 + 32 + p] = s2;
    }
  }
  __syncthreads();
  // Phase C: U chunk sums; wave w owns d in [w*16, w*16+16)
  short8_t a[4];
#pragma unroll
  for (int mt = 0; mt < 4; ++mt) a[mt] = *(short8_t*)&sm.h.SPL[mt * 16 + ml][kq];
  floatx4 acc3[4] = {};
#pragma unroll
  for (int mt = 0; mt < 4; ++mt)
    acc3[mt] = __builtin_amdgcn_mfma_f32_16x16x32_bf16(a[mt], bgv, acc3[mt], 0, 0, 0);
#pragma unroll
  for (int mt = 0; mt < 4; ++mt) {
    int d = w * 16 + ml;
    short4 o;
    o.x = f2bf(acc3[mt][0]);
    o.y = f2bf(acc3[mt][1]);
    o.z = f2bf(acc3[mt][2]);
    o.w = f2bf(acc3[mt][3]);
    *(short4*)&UT[(bc * 256 + d) * 64 + mt * 16 + quad * 4] = o;
  }
}

// ---------------- scanE: m1/sg token scans + UT chunk prefix (merged) ------
// Blocks 0..259: token scans. Blocks 260..1283: coalesced E — wave w owns
// chunk-group [w*16,w*16+16), lanes = 64 consecutive q -> 128B transactions;
// cross-wave stitch via LDS.
__global__ void scanE(float* __restrict__ m1cT, float* __restrict__ m1sT,
                      float* __restrict__ sg, short* __restrict__ UT) {
  __shared__ float wsum[4];
  __shared__ float stot[4][64];
  int blk = blockIdx.x;
  int tid = threadIdx.x;
  if (blk >= 260) {
    int eb = blk - 260;               // 0..1023
    int w = tid >> 6, lane = tid & 63;
    int pi = eb * 64 + lane;          // 64 consecutive pi per block
    int q = pi & 63;
    int d = (pi >> 6) & 255;
    int b = pi >> 14;
    const int cs = 256 * 64;
    int base = ((b * NC) * 256 + d) * 64 + q;
    short v[16];
#pragma unroll
    for (int c = 0; c < 16; ++c) v[c] = UT[base + (w * 16 + c) * cs];
    float tot = 0.f;
#pragma unroll
    for (int c = 0; c < 16; ++c) tot += bf2f(v[c]);
    stot[w][lane] = tot;
    __syncthreads();
    float run = 0.f;
    for (int ww = 0; ww < w; ++ww) run += stot[ww][lane];
#pragma unroll
    for (int c = 0; c < 16; ++c) {
      UT[base + (w * 16 + c) * cs] = f2bf(run);
      run += bf2f(v[c]);
    }
    return;
  }
  int lane = tid & 63, w = tid >> 6;
  float* arr;
  int base;
  if (blk < 256) {
    arr = (blk < 128) ? m1cT : m1sT;
    base = (blk & 127) * L_;
  } else {
    arr = sg;
    base = (blk - 256) * L_;
  }
  int sbase = base + w * 512;
  float v[8];
#pragma unroll
  for (int i = 0; i < 8; ++i) v[i] = arr[sbase + i * 64 + lane];
  float carry = 0.f;
#pragma unroll
  for (int i = 0; i < 8; ++i) {
    float vv = v[i];
#pragma unroll
    for (int off = 1; off < 64; off <<= 1) {
      float n = __shfl_up(vv, off, 64);
      if (lane >= off) vv += n;
    }
    vv += carry;
    v[i] = vv;
    carry = __shfl(vv, 63, 64);
  }
  if (lane == 0) wsum[w] = carry;
  __syncthreads();
  float off = 0.f;
  for (int ww = 0; ww < w; ++ww) off += wsum[ww];
#pragma unroll
  for (int i = 0; i < 8; ++i) arr[sbase + i * 64 + lane] = v[i] + off;
}

// ---------------- fgOut: retrieval + pos_out + LN + gemm2 -> out -----------
// Prefetched UT/gvT/W1OT frags + x residual at entry; coalesced float4
// epilogue through LDS.
struct __align__(16) FGMem {
  short SL[32][40];
  short PR[32][40];
  float CMB[32][260];
  short CBN[32][280];
  float LG[256], LB[256];
  float scl[32], mu_s[32], rs_s[32];
};
__global__ __launch_bounds__(1024, 4) void fgOut(const short* __restrict__ UT,
                                                 const short* __restrict__ SPbf,
                                                 const short* __restrict__ K2bf,
                                                 const short* __restrict__ gvT,
                                                 const float* __restrict__ sgc,
                                                 const float* __restrict__ m1cT,
                                                 const float* __restrict__ m1sT,
                                                 const float* __restrict__ qc,
                                                 const float* __restrict__ qs,
                                                 const short* __restrict__ W1OT,
                                                 const float* __restrict__ b_mem1o,
                                                 const float* __restrict__ ln_g,
                                                 const float* __restrict__ ln_b,
                                                 const short* __restrict__ WO,
                                                 const float* __restrict__ b_out,
                                                 const float* __restrict__ x,
                                                 float* __restrict__ out) {
  __shared__ FGMem sm;
  int tid5 = threadIdx.x;
  int bc = blockIdx.x;
  int lbase = bc * CL;
  int bb = bc >> 6, lloc = (bc & 63) * 32;
  int lane = tid5 & 63, w = tid5 >> 6;
  int ml = lane & 15, quad = lane >> 4, kq = quad * 8;
  int d0 = w * 16;
  // ---- entry prefetches (consumed after barriers; hide HBM latency) ----
  short8_t ub0 = *(const short8_t*)&UT[(bc * 256 + d0 + ml) * 64 + kq];
  short8_t ub1 = *(const short8_t*)&UT[(bc * 256 + d0 + ml) * 64 + 32 + kq];
  short8_t gvb = *(const short8_t*)&gvT[(bc * 256 + d0 + ml) * 32 + kq];
  short8_t w1b = *(const short8_t*)&W1OT[(d0 + ml) * 32 + kq];
  const float4* x4 = (const float4*)&x[lbase * 256];
  float4 xp0 = x4[tid5];
  float4 xp1 = x4[tid5 + 1024];
  if (tid5 < 32) sm.scl[tid5] = rsqrtf(fmaxf(sgc[lbase + tid5], 1.f)) * INV_SQRT_P;
  if (tid5 >= 256 && tid5 < 512) {
    int d = tid5 - 256;
    sm.LG[d] = ln_g[d];
    sm.LB[d] = ln_b[d];
  }
  short8_t ka0 = *(const short8_t*)&K2bf[(lbase + ml) * 64 + kq];
  short8_t ka1 = *(const short8_t*)&K2bf[(lbase + 16 + ml) * 64 + kq];
  short8_t kb0 = *(const short8_t*)&K2bf[(lbase + ml) * 64 + 32 + kq];
  short8_t kb1 = *(const short8_t*)&K2bf[(lbase + 16 + ml) * 64 + 32 + kq];
  if (w == 0) {
    // S = K2 @ SP^T, mask, write SL
    floatx4 sacc[2][2] = {};
#pragma unroll
    for (int ks2 = 0; ks2 < 2; ++ks2) {
      short8_t a0 = (ks2 == 0) ? ka0 : kb0;
      short8_t a1 = (ks2 == 0) ? ka1 : kb1;
      short8_t b0 = *(const short8_t*)&SPbf[(lbase + ml) * 64 + ks2 * 32 + kq];
      short8_t b1 = *(const short8_t*)&SPbf[(lbase + 16 + ml) * 64 + ks2 * 32 + kq];
      sacc[0][0] = __builtin_amdgcn_mfma_f32_16x16x32_bf16(a0, b0, sacc[0][0], 0, 0, 0);
      sacc[0][1] = __builtin_amdgcn_mfma_f32_16x16x32_bf16(a0, b1, sacc[0][1], 0, 0, 0);
      sacc[1][0] = __builtin_amdgcn_mfma_f32_16x16x32_bf16(a1, b0, sacc[1][0], 0, 0, 0);
      sacc[1][1] = __builtin_amdgcn_mfma_f32_16x16x32_bf16(a1, b1, sacc[1][1], 0, 0, 0);
    }
#pragma unroll
    for (int mt = 0; mt < 2; ++mt)
#pragma unroll
      for (int nt = 0; nt < 2; ++nt)
#pragma unroll
        for (int r = 0; r < 4; ++r) {
          int trow = mt * 16 + quad * 4 + r;
          int scol = nt * 16 + ml;
          float v = (scol <= trow) ? sacc[mt][nt][r] : 0.f;
          sm.SL[trow][scol] = f2bf(v);
        }
  } else {
    // PR prep: 1024 items over 960 threads (waves 1-15)
    int t7 = tid5 - 64;
    for (int i = t7; i < 1024; i += 960) {
      int pp = i >> 5, t = i & 31;
      int gT = (bb * 32 + pp) * L_ + lloc + t;
      int g = (lbase + t) * 32 + pp;
      sm.PR[t][pp] = f2bf((m1cT[gT] * qc[g] + m1sT[gT] * qs[g]) * INV_SQRT_P);
    }
  }
  __syncthreads();
  // Part 1: K2 @ Uprev (both k-halves); B-frags were prefetched
  floatx4 acc[2] = {};
  acc[0] = __builtin_amdgcn_mfma_f32_16x16x32_bf16(ka0, ub0, acc[0], 0, 0, 0);
  acc[1] = __builtin_amdgcn_mfma_f32_16x16x32_bf16(ka1, ub0, acc[1], 0, 0, 0);
  acc[0] = __builtin_amdgcn_mfma_f32_16x16x32_bf16(kb0, ub1, acc[0], 0, 0, 0);
  acc[1] = __builtin_amdgcn_mfma_f32_16x16x32_bf16(kb1, ub1, acc[1], 0, 0, 0);
  // Part 2: S @ gv
  {
    short8_t a0 = *(short8_t*)&sm.SL[ml][kq];
    short8_t a1 = *(short8_t*)&sm.SL[16 + ml][kq];
    acc[0] = __builtin_amdgcn_mfma_f32_16x16x32_bf16(a0, gvb, acc[0], 0, 0, 0);
    acc[1] = __builtin_amdgcn_mfma_f32_16x16x32_bf16(a1, gvb, acc[1], 0, 0, 0);
  }
  // pos_out MFMA
  floatx4 macc[2] = {};
  {
    short8_t a0 = *(short8_t*)&sm.PR[ml][kq];
    short8_t a1 = *(short8_t*)&sm.PR[16 + ml][kq];
    macc[0] = __builtin_amdgcn_mfma_f32_16x16x32_bf16(a0, w1b, macc[0], 0, 0, 0);
    macc[1] = __builtin_amdgcn_mfma_f32_16x16x32_bf16(a1, w1b, macc[1], 0, 0, 0);
  }
  {
    int d = d0 + ml;
    float bm = b_mem1o[d];
#pragma unroll
    for (int mt = 0; mt < 2; ++mt)
#pragma unroll
      for (int r = 0; r < 4; ++r) {
        int t = mt * 16 + quad * 4 + r;
        sm.CMB[t][d] = acc[mt][r] * sm.scl[t] + macc[mt][r] + bm;
      }
  }
  __syncthreads();
  // LN stats: 32 threads per token, 8 elements each
  {
    int t = tid5 >> 5, g = tid5 & 31;
    float s = 0.f, s2 = 0.f;
#pragma unroll
    for (int j = 0; j < 8; ++j) {
      float v = sm.CMB[t][g + j * 32];
      s += v;
      s2 += v * v;
    }
#pragma unroll
    for (int m = 1; m < 32; m <<= 1) {
      s += __shfl_xor(s, m, 64);
      s2 += __shfl_xor(s2, m, 64);
    }
    if (g == 0) {
      float mu = s / (float)D_;
      float var = s2 / (float)D_ - mu * mu;
      sm.mu_s[t] = mu;
      sm.rs_s[t] = rsqrtf(var + 1e-5f);
    }
  }
  __syncthreads();
  // normalize -> CBN (bf16) in LDS
#pragma unroll
  for (int it = 0; it < 8; ++it) {
    int i = it * 1024 + tid5;
    int t = i >> 8, d = i & 255;
    sm.CBN[t][d] = f2bf((sm.CMB[t][d] - sm.mu_s[t]) * sm.rs_s[t] * sm.LG[d] + sm.LB[d]);
  }
  __syncthreads();
  // gemm2: CBN @ WO + b_out -> CMB (reuse; dead after CBN built)
  floatx4 acc2[2] = {};
#pragma unroll
  for (int kt = 0; kt < 8; ++kt) {
    short8_t a0 = *(short8_t*)&sm.CBN[ml][kt * 32 + kq];
    short8_t a1 = *(short8_t*)&sm.CBN[16 + ml][kt * 32 + kq];
    short8_t b = *(const short8_t*)&WO[(d0 + ml) * 256 + kt * 32 + kq];
    acc2[0] = __builtin_amdgcn_mfma_f32_16x16x32_bf16(a0, b, acc2[0], 0, 0, 0);
    acc2[1] = __builtin_amdgcn_mfma_f32_16x16x32_bf16(a1, b, acc2[1], 0, 0, 0);
  }
  {
    int n = d0 + ml;
    float bv = b_out[n];
#pragma unroll
    for (int mt = 0; mt < 2; ++mt)
#pragma unroll
      for (int r = 0; r < 4; ++r) {
        int t = mt * 16 + quad * 4 + r;
        sm.CMB[t][n] = acc2[mt][r] + bv;
      }
  }
  __syncthreads();
  // coalesced float4 epilogue: out = x + CMB
  {
    float4* o4 = (float4*)&out[lbase * 256];
#pragma unroll
    for (int k = 0; k < 2; ++k) {
      int idx4 = tid5 + k * 1024;
      int t = idx4 >> 6, dd = (idx4 & 63) * 4;
      float4 xp = (k == 0) ? xp0 : xp1;
      float4 o;
      o.x = xp.x + sm.CMB[t][dd + 0];
      o.y = xp.y + sm.CMB[t][dd + 1];
      o.z = xp.z + sm.CMB[t][dd + 2];
      o.w = xp.w + sm.CMB[t][dd + 3];
      o4[idx4] = o;
    }
  }
}

extern "C" void kernel_launch(void* const* d_in, const int* in_sizes, int n_in,
                              void* d_out, int out_size, void* d_ws, size_t ws_size,
                              hipStream_t stream) {
  const float* x = (const float*)d_in[0];
  const float* pos = (const float*)d_in[1];
  const float* w_mem1v = (const float*)d_in[2];
  const float* b_mem1v = (const float*)d_in[3];
  const float* w_mem1o = (const float*)d_in[4];
  const float* b_mem1o = (const float*)d_in[5];
  const float* w_off = (const float*)d_in[6];
  const float* b_off = (const float*)d_in[7];
  const float* w_key = (const float*)d_in[8];
  const float* b_key = (const float*)d_in[9];
  const float* w_val = (const float*)d_in[10];
  const float* b_val = (const float*)d_in[11];
  const float* w_sk1 = (const float*)d_in[12];
  const float* b_sk1 = (const float*)d_in[13];
  const float* w_sk2 = (const float*)d_in[14];
  const float* b_sk2 = (const float*)d_in[15];
  const float* w_gate = (const float*)d_in[16];
  const float* b_gate = (const float*)d_in[17];
  const float* ln_g = (const float*)d_in[18];
  const float* ln_b = (const float*)d_in[19];
  const float* w_out = (const float*)d_in[20];
  const float* b_out = (const float*)d_in[21];
  float* out = (float*)d_out;
  float* ws = (float*)d_ws;

  const int BLP = B_ * L_ * P_;  // 262144
  const int BLD = B_ * L_ * D_;  // 2097152
  float* m1cT = ws;
  float* m1sT = m1cT + BLP;
  float* qc = m1sT + BLP;
  float* qs = qc + BLP;
  float* sg = qs + BLP;
  float* poff = sg + B_ * L_;
  float* ctxsum = poff + L_ * P_;              // B*64*256 = 65536 floats
  short* UT = (short*)(ctxsum + B_ * 64 * 256);
  short* xbf = UT + (size_t)B_ * NC * 256 * 64;
  short* ctxbf = xbf + BLD;           // unused (layout stability)
  short* hs = ctxbf + BLD;            // unused (layout stability)
  short* gvT = hs + BLD;
  short* K2bf = gvT + BLD;            // B*L*64
  short* SPbf = K2bf + B_ * L_ * 64;  // B*L*64
  short* WA = SPbf + B_ * L_ * 64;
  short* W1 = WA + 384 * 256;
  short* WO = W1 + 256 * 512;
  short* W2T = WO + 256 * 256;
  short* W1OT = W2T + 32 * 256;

  wprep<<<1728, 256, 0, stream>>>(x, pos, w_val, w_mem1v, w_off, b_off, w_key, w_gate,
                                  w_sk1, w_out, w_sk2, w_mem1o, WA, W1, WO, W2T, W1OT,
                                  xbf, poff, ctxsum);
  gemmA3<<<516, 768, 0, stream>>>(xbf, WA, pos, poff, b_mem1v, b_key, b_gate, b_val,
                                  m1cT, m1sT, qc, qs, K2bf, gvT, sg, ctxsum);
  gemmCD<<<256, 1024, 0, stream>>>(xbf, x, ctxsum, W1, b_sk1, W2T, b_sk2, gvT, SPbf, UT);
  scanE<<<1284, 256, 0, stream>>>(m1cT, m1sT, sg, UT);
  fgOut<<<256, 1024, 0, stream>>>(UT, SPbf, K2bf, gvT, sg, m1cT, m1sT, qc, qs,
                                  W1OT, b_mem1o, ln_g, ln_b, WO, b_out, x, out);
}